// Round 2
// baseline (622.944 us; speedup 1.0000x reference)
//
#include <hip/hip_runtime.h>
#include <hip/hip_bf16.h>
#include <cstdint>
#include <cstddef>

using bf16    = __bf16;
using bf16x4  = __attribute__((ext_vector_type(4))) __bf16;
using bf16x8  = __attribute__((ext_vector_type(8))) __bf16;
using floatx4 = __attribute__((ext_vector_type(4))) float;

__device__ __forceinline__ void async_cp16(const bf16* g, bf16* l) {
    // gfx950: direct global->LDS DMA, 16B per lane, LDS dest = wave-uniform base + lane*16
    __builtin_amdgcn_global_load_lds(
        (__attribute__((address_space(1))) void*)const_cast<bf16*>(g),
        (__attribute__((address_space(3))) void*)l,
        16, 0, 0);
}

// ---------------------------------------------------------------------------
// prep: xv = bf16(x*tmv + (1-tmv)*xx), xr = bf16(x*tmr + (1-tmr)*xx)
// ---------------------------------------------------------------------------
__global__ __launch_bounds__(256) void prep_kernel(
    const float* __restrict__ x, const float* __restrict__ tmv,
    const float* __restrict__ tmr, const float* __restrict__ xxp,
    bf16* __restrict__ xv, bf16* __restrict__ xr, int nvec, int cvec_mask) {
    int vid = blockIdx.x * blockDim.x + threadIdx.x;
    if (vid >= nvec) return;
    int c = (vid & cvec_mask) * 4;
    float4 xi = ((const float4*)x)[vid];
    float4 mv = *(const float4*)&tmv[c];
    float4 mr = *(const float4*)&tmr[c];
    float4 x0 = *(const float4*)&xxp[c];
    float xa[4]  = {xi.x, xi.y, xi.z, xi.w};
    float mva[4] = {mv.x, mv.y, mv.z, mv.w};
    float mra[4] = {mr.x, mr.y, mr.z, mr.w};
    float x0a[4] = {x0.x, x0.y, x0.z, x0.w};
    bf16x4 ov, og;
#pragma unroll
    for (int u = 0; u < 4; ++u) {
        ov[u] = (bf16)(xa[u] * mva[u] + (1.0f - mva[u]) * x0a[u]);
        og[u] = (bf16)(xa[u] * mra[u] + (1.0f - mra[u]) * x0a[u]);
    }
    *(bf16x4*)&xv[(size_t)vid * 4] = ov;
    *(bf16x4*)&xr[(size_t)vid * 4] = og;
}

// one launch converting all three CxC fp32 weights to bf16
__global__ __launch_bounds__(256) void cvt3_kernel(
    const float* __restrict__ w0, const float* __restrict__ w1,
    const float* __restrict__ w2, bf16* __restrict__ o0,
    bf16* __restrict__ o1, bf16* __restrict__ o2, int nvec_each) {
    int vid = blockIdx.x * blockDim.x + threadIdx.x;
    const float* src;
    bf16* dst;
    if (vid < nvec_each) {
        src = w0; dst = o0;
    } else if (vid < 2 * nvec_each) {
        src = w1; dst = o1; vid -= nvec_each;
    } else {
        src = w2; dst = o2; vid -= 2 * nvec_each;
    }
    float4 f = ((const float4*)src)[vid];
    bf16x4 o;
    o[0] = (bf16)f.x; o[1] = (bf16)f.y; o[2] = (bf16)f.z; o[3] = (bf16)f.w;
    *(bf16x4*)&dst[(size_t)vid * 4] = o;
}

// ---------------------------------------------------------------------------
// NT GEMM: C[m][n] = sum_k A[m][k]*Bw[n][k]; 128x128 tile, BK=32, 4 waves.
// MFMA-ready LDS layout: slot s (16B) holds global chunk
//   (row = (s>>6)*16 + (s&15), kchunk = (s>>4)&3)
// so fragment reads are lane-linear (conflict-free, immediate offsets).
// EPI: 0 = store bf16; 1 = store bf16(sigmoid(acc)*Vaux); 2 = store fp32.
// ---------------------------------------------------------------------------
template <int EPI>
__global__ __launch_bounds__(256) void gemm_bt(
    const bf16* __restrict__ A, const bf16* __restrict__ Bw,
    const bf16* __restrict__ Vaux, bf16* __restrict__ Ob,
    float* __restrict__ Of, int M, int N, int K) {
    __shared__ __align__(16) bf16 sA[128 * 32];
    __shared__ __align__(16) bf16 sB[128 * 32];

    const int tid  = threadIdx.x;
    const int wave = tid >> 6;
    const int lane = tid & 63;
    const int quad = lane >> 4;
    const int l16  = lane & 15;
    const int m0   = blockIdx.y * 128;
    const int n0   = blockIdx.x * 128;
    const int wm   = (wave >> 1) * 64;  // wave's row offset in tile
    const int wn   = (wave & 1) * 64;   // wave's col offset in tile

    floatx4 acc[4][4];
#pragma unroll
    for (int i = 0; i < 4; ++i)
#pragma unroll
        for (int j = 0; j < 4; ++j) acc[i][j] = (floatx4){0.f, 0.f, 0.f, 0.f};

    // staging map (MFMA-ready): thread t covers LDS slots t and t+256.
    // slot t      -> row (t>>6)*16 + (t&15),      kchunk (t>>4)&3
    // slot t+256  -> row 64 + (t>>6)*16 + (t&15), same kchunk
    const int row0 = ((tid >> 6) << 4) | (tid & 15);
    const int col0 = ((tid >> 4) & 3) << 3;  // element offset in 32-wide k-slab
    const bf16* gA0 = A + (size_t)(m0 + row0) * K + col0;
    const bf16* gA1 = gA0 + (size_t)64 * K;
    const bf16* gB0 = Bw + (size_t)(n0 + row0) * K + col0;
    const bf16* gB1 = gB0 + (size_t)64 * K;
    bf16* lA0 = &sA[wave * 512];
    bf16* lA1 = &sA[2048 + wave * 512];
    bf16* lB0 = &sB[wave * 512];
    bf16* lB1 = &sB[2048 + wave * 512];

    const int kIters = K >> 5;
    for (int it = 0; it < kIters; ++it) {
        __syncthreads();  // previous iter's LDS readers done
        async_cp16(gA0, lA0);
        async_cp16(gA1, lA1);
        async_cp16(gB0, lB0);
        async_cp16(gB1, lB1);
        gA0 += 32; gA1 += 32; gB0 += 32; gB1 += 32;
        __syncthreads();  // staging drained (vmcnt(0) before barrier)

        // lane-linear fragment reads: addr = ((wm>>4)+i)*512 + lane*8 elements
        bf16x8 af[4], bfg[4];
#pragma unroll
        for (int i = 0; i < 4; ++i)
            af[i] = *(const bf16x8*)&sA[(((wm >> 4) + i) << 9) + (lane << 3)];
#pragma unroll
        for (int j = 0; j < 4; ++j)
            bfg[j] = *(const bf16x8*)&sB[(((wn >> 4) + j) << 9) + (lane << 3)];
#pragma unroll
        for (int i = 0; i < 4; ++i)
#pragma unroll
            for (int j = 0; j < 4; ++j)
                acc[i][j] = __builtin_amdgcn_mfma_f32_16x16x32_bf16(
                    af[i], bfg[j], acc[i][j], 0, 0, 0);
    }

    // epilogue: C/D layout (16x16x32): col = lane&15, row = quad*4 + reg
    const int rbase = quad * 4;
#pragma unroll
    for (int i = 0; i < 4; ++i) {
#pragma unroll
        for (int j = 0; j < 4; ++j) {
            const int col = n0 + wn + j * 16 + l16;
#pragma unroll
            for (int r = 0; r < 4; ++r) {
                const int row = m0 + wm + i * 16 + rbase + r;
                const size_t o = (size_t)row * N + col;
                const float va = acc[i][j][r];
                if (EPI == 0) {
                    Ob[o] = (bf16)va;
                } else if (EPI == 1) {
                    const float vv = (float)Vaux[o];
                    const float sg = 1.0f / (1.0f + __expf(-va));
                    Ob[o] = (bf16)(sg * vv);
                } else {
                    Of[o] = va;
                }
            }
        }
    }
}

extern "C" void kernel_launch(void* const* d_in, const int* in_sizes, int n_in,
                              void* d_out, int out_size, void* d_ws, size_t ws_size,
                              hipStream_t stream) {
    // inputs: 0:x 1:time_first 2:tmk 3:tmv 4:tmr 5:xx 6:aa 7:bb 8:pp
    //         9:w_key 10:w_value 11:w_rec 12:w_out
    const int C = in_sizes[1];              // 2048
    const int M = in_sizes[0] / C;          // B*T = 8192
    const size_t MC = (size_t)M * C;
    const size_t CC = (size_t)C * C;

    const float* x   = (const float*)d_in[0];
    const float* tmv = (const float*)d_in[3];
    const float* tmr = (const float*)d_in[4];
    const float* xxp = (const float*)d_in[5];
    const float* wv  = (const float*)d_in[10];
    const float* wr  = (const float*)d_in[11];
    const float* wo  = (const float*)d_in[12];
    float* out = (float*)d_out;

    uint8_t* ws = (uint8_t*)d_ws;
    // layout (bf16): xv[MC], xr[MC], v[MC], wv[CC], wr[CC], wo[CC]
    const size_t need_full = MC * 6 + CC * 6;
    bf16* xv;
    bf16* xr;
    bf16* vbuf;
    bf16* wvb;
    bf16* wrb;
    bf16* wob;
    if (ws_size >= need_full) {
        xv   = (bf16*)(ws);
        xr   = (bf16*)(ws + MC * 2);
        vbuf = (bf16*)(ws + MC * 4);
        wvb  = (bf16*)(ws + MC * 6);
        wrb  = (bf16*)(ws + MC * 6 + CC * 2);
        wob  = (bf16*)(ws + MC * 6 + CC * 4);
    } else {
        // fallback: park v (bf16) in the front half of d_out (fp32, 2x the bytes);
        // fully consumed by GEMM_r before GEMM_out overwrites d_out.
        xv   = (bf16*)(ws);
        xr   = (bf16*)(ws + MC * 2);
        vbuf = (bf16*)d_out;
        wvb  = (bf16*)(ws + MC * 4);
        wrb  = (bf16*)(ws + MC * 4 + CC * 2);
        wob  = (bf16*)(ws + MC * 4 + CC * 4);
    }
    bf16* rwkv = xv;  // xv is dead after GEMM_v

    const int nvecX = (int)(MC / 4);
    prep_kernel<<<(nvecX + 255) / 256, 256, 0, stream>>>(x, tmv, tmr, xxp, xv, xr,
                                                         nvecX, C / 4 - 1);
    const int nvecW = (int)(CC / 4);
    cvt3_kernel<<<(3 * nvecW + 255) / 256, 256, 0, stream>>>(wv, wr, wo, wvb, wrb,
                                                             wob, nvecW);

    dim3 grid(C / 128, M / 128);  // (16, 64)
    // v = xv @ Wv^T            (store bf16)
    gemm_bt<0><<<grid, 256, 0, stream>>>(xv, wvb, nullptr, vbuf, nullptr, M, C, C);
    // rwkv = sigmoid(xr @ Wr^T) * v   (store bf16; wkv == v, see analysis)
    gemm_bt<1><<<grid, 256, 0, stream>>>(xr, wrb, vbuf, rwkv, nullptr, M, C, C);
    // out = rwkv @ Wo^T        (store fp32)
    gemm_bt<2><<<grid, 256, 0, stream>>>(rwkv, wob, nullptr, nullptr, out, M, C, C);
}

// Round 3
// 475.293 us; speedup vs baseline: 1.3107x; 1.3107x over previous
//
#include <hip/hip_runtime.h>
#include <hip/hip_bf16.h>
#include <cstdint>
#include <cstddef>

using bf16    = __bf16;
using bf16x8  = __attribute__((ext_vector_type(8))) __bf16;
using floatx4 = __attribute__((ext_vector_type(4))) float;

// Swizzled ("packet") layout for all bf16 GEMM operands:
//   packet = 1024B = one (16-row x 32-k) block of a row-major [R x K] matrix
//   packet index  = (row>>4) * (K>>5) + (k>>5)
//   lane-in-packet l (16B)  holds  row = 16*(row>>4) + (l&15), k-chunk l>>4 (8 elems)
// => element (row,k) lives at  packet*512 + (((k>>3)&3)*16 + (row&15))*8 + (k&7)
// This makes global_load_lds staging read 1024 contiguous bytes per wave AND
// lands MFMA-ready in LDS (lane-linear, conflict-free fragment reads).

__device__ __forceinline__ void async_cp16(const bf16* g, bf16* l) {
    __builtin_amdgcn_global_load_lds(
        (__attribute__((address_space(1))) void*)const_cast<bf16*>(g),
        (__attribute__((address_space(3))) void*)l,
        16, 0, 0);
}

// ---------------------------------------------------------------------------
// prep: xv = bf16(x*tmv + (1-tmv)*xx), xr = bf16(x*tmr + (1-tmr)*xx), swizzled.
// block = 256 thr covers 16 rows x 128 cols; thread t: packet p=t>>6, lane l=t&63.
// ---------------------------------------------------------------------------
__global__ __launch_bounds__(256) void prep_swz(
    const float* __restrict__ x, const float* __restrict__ tmv,
    const float* __restrict__ tmr, const float* __restrict__ xxp,
    bf16* __restrict__ xv, bf16* __restrict__ xr, int C) {
    const int t = threadIdx.x;
    const int p = t >> 6, l = t & 63;
    const int r0 = blockIdx.y << 4;
    const int c0 = blockIdx.x << 7;
    const int row = r0 + (l & 15);
    const int k = c0 + (p << 5) + ((l >> 4) << 3);

    const float4* xi = (const float4*)&x[(size_t)row * C + k];
    float4 a0 = xi[0], a1 = xi[1];
    float4 mv0 = *(const float4*)&tmv[k], mv1 = *(const float4*)&tmv[k + 4];
    float4 mr0 = *(const float4*)&tmr[k], mr1 = *(const float4*)&tmr[k + 4];
    float4 x00 = *(const float4*)&xxp[k], x01 = *(const float4*)&xxp[k + 4];

    float xa[8]  = {a0.x, a0.y, a0.z, a0.w, a1.x, a1.y, a1.z, a1.w};
    float mva[8] = {mv0.x, mv0.y, mv0.z, mv0.w, mv1.x, mv1.y, mv1.z, mv1.w};
    float mra[8] = {mr0.x, mr0.y, mr0.z, mr0.w, mr1.x, mr1.y, mr1.z, mr1.w};
    float x0a[8] = {x00.x, x00.y, x00.z, x00.w, x01.x, x01.y, x01.z, x01.w};

    bf16x8 ov, og;
#pragma unroll
    for (int u = 0; u < 8; ++u) {
        ov[u] = (bf16)(xa[u] * mva[u] + (1.0f - mva[u]) * x0a[u]);
        og[u] = (bf16)(xa[u] * mra[u] + (1.0f - mra[u]) * x0a[u]);
    }
    const size_t off = ((size_t)(r0 >> 4) * (C >> 5) + (c0 >> 5) + p) * 512 + l * 8;
    *(bf16x8*)&xv[off] = ov;
    *(bf16x8*)&xr[off] = og;
}

// three CxC fp32 weights -> swizzled bf16 (blockIdx.z selects weight)
__global__ __launch_bounds__(256) void cvt_swz(
    const float* __restrict__ w0, const float* __restrict__ w1,
    const float* __restrict__ w2, bf16* __restrict__ o0,
    bf16* __restrict__ o1, bf16* __restrict__ o2, int C) {
    const float* w = blockIdx.z == 0 ? w0 : (blockIdx.z == 1 ? w1 : w2);
    bf16* o = blockIdx.z == 0 ? o0 : (blockIdx.z == 1 ? o1 : o2);
    const int t = threadIdx.x;
    const int p = t >> 6, l = t & 63;
    const int r0 = blockIdx.y << 4;
    const int c0 = blockIdx.x << 7;
    const int row = r0 + (l & 15);
    const int k = c0 + (p << 5) + ((l >> 4) << 3);
    const float4* wi = (const float4*)&w[(size_t)row * C + k];
    float4 a0 = wi[0], a1 = wi[1];
    float wa[8] = {a0.x, a0.y, a0.z, a0.w, a1.x, a1.y, a1.z, a1.w};
    bf16x8 ov;
#pragma unroll
    for (int u = 0; u < 8; ++u) ov[u] = (bf16)wa[u];
    const size_t off = ((size_t)(r0 >> 4) * (C >> 5) + (c0 >> 5) + p) * 512 + l * 8;
    *(bf16x8*)&o[off] = ov;
}

// ---------------------------------------------------------------------------
// NT GEMM on swizzled operands: C[m][n] = sum_k A[m][k]*Bw[n][k].
// 128x128 tile, BK=32, 4 waves. Staging = 4 x 1KB-contiguous global_load_lds
// per wave per iter; fragment reads lane-linear (conflict-free).
// EPI: 0 = store bf16 swizzled; 1 = store bf16(sigmoid(acc)*Vaux) swizzled
//      (Vaux also swizzled); 2 = store fp32 row-major.
// ---------------------------------------------------------------------------
template <int EPI>
__global__ __launch_bounds__(256) void gemm_swz(
    const bf16* __restrict__ A, const bf16* __restrict__ Bw,
    const bf16* __restrict__ Vaux, bf16* __restrict__ Ob,
    float* __restrict__ Of, int M, int N, int K) {
    __shared__ __align__(16) bf16 sA[128 * 32];
    __shared__ __align__(16) bf16 sB[128 * 32];

    const int tid  = threadIdx.x;
    const int wave = tid >> 6;
    const int lane = tid & 63;
    const int quad = lane >> 4;
    const int l16  = lane & 15;
    const int m0   = blockIdx.y * 128;
    const int n0   = blockIdx.x * 128;
    const int wm   = (wave >> 1) * 64;
    const int wn   = (wave & 1) * 64;
    const int kslabs = K >> 5;

    floatx4 acc[4][4];
#pragma unroll
    for (int i = 0; i < 4; ++i)
#pragma unroll
        for (int j = 0; j < 4; ++j) acc[i][j] = (floatx4){0.f, 0.f, 0.f, 0.f};

    // staging: wave w instruction A0 covers row-block (m0>>4)+w, A1 = +4
    const bf16* gA0 = A + ((size_t)((m0 >> 4) + wave) * kslabs) * 512 + lane * 8;
    const bf16* gA1 = gA0 + (size_t)4 * kslabs * 512;
    const bf16* gB0 = Bw + ((size_t)((n0 >> 4) + wave) * kslabs) * 512 + lane * 8;
    const bf16* gB1 = gB0 + (size_t)4 * kslabs * 512;
    bf16* lA0 = &sA[wave * 512];
    bf16* lA1 = &sA[2048 + wave * 512];
    bf16* lB0 = &sB[wave * 512];
    bf16* lB1 = &sB[2048 + wave * 512];

    for (int it = 0; it < kslabs; ++it) {
        __syncthreads();
        async_cp16(gA0, lA0);
        async_cp16(gA1, lA1);
        async_cp16(gB0, lB0);
        async_cp16(gB1, lB1);
        gA0 += 512; gA1 += 512; gB0 += 512; gB1 += 512;
        __syncthreads();

        bf16x8 af[4], bfg[4];
#pragma unroll
        for (int i = 0; i < 4; ++i)
            af[i] = *(const bf16x8*)&sA[(((wm >> 4) + i) << 9) + (lane << 3)];
#pragma unroll
        for (int j = 0; j < 4; ++j)
            bfg[j] = *(const bf16x8*)&sB[(((wn >> 4) + j) << 9) + (lane << 3)];
#pragma unroll
        for (int i = 0; i < 4; ++i)
#pragma unroll
            for (int j = 0; j < 4; ++j)
                acc[i][j] = __builtin_amdgcn_mfma_f32_16x16x32_bf16(
                    af[i], bfg[j], acc[i][j], 0, 0, 0);
    }

    // epilogue: C/D layout (16x16x32): col = lane&15, row = quad*4 + reg
    const int rbase = quad * 4;
#pragma unroll
    for (int i = 0; i < 4; ++i) {
        const int rb = ((m0 + wm) >> 4) + i;  // global row-block
#pragma unroll
        for (int j = 0; j < 4; ++j) {
            const int col = n0 + wn + j * 16 + l16;
            if (EPI == 2) {
#pragma unroll
                for (int r = 0; r < 4; ++r) {
                    const int row = m0 + wm + i * 16 + rbase + r;
                    Of[(size_t)row * N + col] = acc[i][j][r];
                }
            } else {
                // swizzled store: elem = packet*512 + (((col>>3)&3)*16 + row15)*8 + (col&7)
                const size_t base = ((size_t)rb * (N >> 5) + (col >> 5)) * 512 +
                                    (size_t)(((col >> 3) & 3) << 4) * 8 + (col & 7);
#pragma unroll
                for (int r = 0; r < 4; ++r) {
                    const size_t o = base + (size_t)(rbase + r) * 8;
                    const float va = acc[i][j][r];
                    if (EPI == 0) {
                        Ob[o] = (bf16)va;
                    } else {
                        const float vv = (float)Vaux[o];
                        const float sg = 1.0f / (1.0f + __expf(-va));
                        Ob[o] = (bf16)(sg * vv);
                    }
                }
            }
        }
    }
}

extern "C" void kernel_launch(void* const* d_in, const int* in_sizes, int n_in,
                              void* d_out, int out_size, void* d_ws, size_t ws_size,
                              hipStream_t stream) {
    // inputs: 0:x 1:time_first 2:tmk 3:tmv 4:tmr 5:xx 6:aa 7:bb 8:pp
    //         9:w_key 10:w_value 11:w_rec 12:w_out
    const int C = in_sizes[1];              // 2048
    const int M = in_sizes[0] / C;          // B*T = 8192
    const size_t MC = (size_t)M * C;
    const size_t CC = (size_t)C * C;

    const float* x   = (const float*)d_in[0];
    const float* tmv = (const float*)d_in[3];
    const float* tmr = (const float*)d_in[4];
    const float* xxp = (const float*)d_in[5];
    const float* wv  = (const float*)d_in[10];
    const float* wr  = (const float*)d_in[11];
    const float* wo  = (const float*)d_in[12];
    float* out = (float*)d_out;

    uint8_t* ws = (uint8_t*)d_ws;
    const size_t need_full = MC * 6 + CC * 6;
    bf16* xv;
    bf16* xr;
    bf16* vbuf;
    bf16* wvb;
    bf16* wrb;
    bf16* wob;
    if (ws_size >= need_full) {
        xv   = (bf16*)(ws);
        xr   = (bf16*)(ws + MC * 2);
        vbuf = (bf16*)(ws + MC * 4);
        wvb  = (bf16*)(ws + MC * 6);
        wrb  = (bf16*)(ws + MC * 6 + CC * 2);
        wob  = (bf16*)(ws + MC * 6 + CC * 4);
    } else {
        // fallback: park v (bf16) in d_out (fp32 => 2x bytes); consumed by
        // GEMM_r before GEMM_out overwrites d_out.
        xv   = (bf16*)(ws);
        xr   = (bf16*)(ws + MC * 2);
        vbuf = (bf16*)d_out;
        wvb  = (bf16*)(ws + MC * 4);
        wrb  = (bf16*)(ws + MC * 4 + CC * 2);
        wob  = (bf16*)(ws + MC * 4 + CC * 4);
    }
    bf16* rwkv = xv;  // xv dead after GEMM_v

    prep_swz<<<dim3(C / 128, M / 16), 256, 0, stream>>>(x, tmv, tmr, xxp, xv, xr, C);
    cvt_swz<<<dim3(C / 128, C / 16, 3), 256, 0, stream>>>(wv, wr, wo, wvb, wrb, wob, C);

    dim3 grid(C / 128, M / 128);  // (16, 64)
    // v = xv @ Wv^T                      (store bf16 swizzled)
    gemm_swz<0><<<grid, 256, 0, stream>>>(xv, wvb, nullptr, vbuf, nullptr, M, C, C);
    // rwkv = sigmoid(xr @ Wr^T) * v      (wkv == v; store bf16 swizzled)
    gemm_swz<1><<<grid, 256, 0, stream>>>(xr, wrb, vbuf, rwkv, nullptr, M, C, C);
    // out = rwkv @ Wo^T                  (store fp32 row-major)
    gemm_swz<2><<<grid, 256, 0, stream>>>(rwkv, wob, nullptr, nullptr, out, M, C, C);
}

// Round 4
// 401.809 us; speedup vs baseline: 1.5503x; 1.1829x over previous
//
#include <hip/hip_runtime.h>
#include <hip/hip_bf16.h>
#include <cstdint>
#include <cstddef>

using bf16    = __bf16;
using bf16x8  = __attribute__((ext_vector_type(8))) __bf16;
using floatx4 = __attribute__((ext_vector_type(4))) float;

// Swizzled ("packet") layout for all bf16 GEMM operands:
//   packet = 1024B = one (16-row x 32-k) block of a row-major [R x K] matrix
//   packet index  = (row>>4) * (K>>5) + (k>>5)
//   lane l (16B) holds row = 16*(row>>4) + (l&15), k-chunk l>>4 (8 elems)
// => element (row,k) at  packet*512 + (((k>>3)&3)*16 + (row&15))*8 + (k&7)
// Staging reads 1024B contiguous per wave; LDS fragment reads are lane-linear.

__device__ __forceinline__ void async_cp16(const bf16* g, bf16* l) {
    __builtin_amdgcn_global_load_lds(
        (__attribute__((address_space(1))) void*)const_cast<bf16*>(g),
        (__attribute__((address_space(3))) void*)l,
        16, 0, 0);
}

// ---------------------------------------------------------------------------
// prep: xv/xr token-mix -> bf16 swizzled
// ---------------------------------------------------------------------------
__global__ __launch_bounds__(256) void prep_swz(
    const float* __restrict__ x, const float* __restrict__ tmv,
    const float* __restrict__ tmr, const float* __restrict__ xxp,
    bf16* __restrict__ xv, bf16* __restrict__ xr, int C) {
    const int t = threadIdx.x;
    const int p = t >> 6, l = t & 63;
    const int r0 = blockIdx.y << 4;
    const int c0 = blockIdx.x << 7;
    const int row = r0 + (l & 15);
    const int k = c0 + (p << 5) + ((l >> 4) << 3);

    const float4* xi = (const float4*)&x[(size_t)row * C + k];
    float4 a0 = xi[0], a1 = xi[1];
    float4 mv0 = *(const float4*)&tmv[k], mv1 = *(const float4*)&tmv[k + 4];
    float4 mr0 = *(const float4*)&tmr[k], mr1 = *(const float4*)&tmr[k + 4];
    float4 x00 = *(const float4*)&xxp[k], x01 = *(const float4*)&xxp[k + 4];

    float xa[8]  = {a0.x, a0.y, a0.z, a0.w, a1.x, a1.y, a1.z, a1.w};
    float mva[8] = {mv0.x, mv0.y, mv0.z, mv0.w, mv1.x, mv1.y, mv1.z, mv1.w};
    float mra[8] = {mr0.x, mr0.y, mr0.z, mr0.w, mr1.x, mr1.y, mr1.z, mr1.w};
    float x0a[8] = {x00.x, x00.y, x00.z, x00.w, x01.x, x01.y, x01.z, x01.w};

    bf16x8 ov, og;
#pragma unroll
    for (int u = 0; u < 8; ++u) {
        ov[u] = (bf16)(xa[u] * mva[u] + (1.0f - mva[u]) * x0a[u]);
        og[u] = (bf16)(xa[u] * mra[u] + (1.0f - mra[u]) * x0a[u]);
    }
    const size_t off = ((size_t)(r0 >> 4) * (C >> 5) + (c0 >> 5) + p) * 512 + l * 8;
    *(bf16x8*)&xv[off] = ov;
    *(bf16x8*)&xr[off] = og;
}

// three CxC fp32 weights -> swizzled bf16
__global__ __launch_bounds__(256) void cvt_swz(
    const float* __restrict__ w0, const float* __restrict__ w1,
    const float* __restrict__ w2, bf16* __restrict__ o0,
    bf16* __restrict__ o1, bf16* __restrict__ o2, int C) {
    const float* w = blockIdx.z == 0 ? w0 : (blockIdx.z == 1 ? w1 : w2);
    bf16* o = blockIdx.z == 0 ? o0 : (blockIdx.z == 1 ? o1 : o2);
    const int t = threadIdx.x;
    const int p = t >> 6, l = t & 63;
    const int r0 = blockIdx.y << 4;
    const int c0 = blockIdx.x << 7;
    const int row = r0 + (l & 15);
    const int k = c0 + (p << 5) + ((l >> 4) << 3);
    const float4* wi = (const float4*)&w[(size_t)row * C + k];
    float4 a0 = wi[0], a1 = wi[1];
    float wa[8] = {a0.x, a0.y, a0.z, a0.w, a1.x, a1.y, a1.z, a1.w};
    bf16x8 ov;
#pragma unroll
    for (int u = 0; u < 8; ++u) ov[u] = (bf16)wa[u];
    const size_t off = ((size_t)(r0 >> 4) * (C >> 5) + (c0 >> 5) + p) * 512 + l * 8;
    *(bf16x8*)&o[off] = ov;
}

// ---------------------------------------------------------------------------
// FUSED v/r GEMM, BK=64: per 128x128 (m,n) tile compute
//   accv = xv@Wv^T, accr = xr@Wr^T  in one K-loop (one drain serves 2 GEMMs,
//   half the barrier rounds of BK=32), then RW = bf16(sigmoid(accr)*accv)
//   stored swizzled. 4 LDS tensors x 16KB = 64KB.
// ---------------------------------------------------------------------------
__global__ __launch_bounds__(256, 2) void gemm_vr(
    const bf16* __restrict__ XV, const bf16* __restrict__ XR,
    const bf16* __restrict__ WV, const bf16* __restrict__ WR,
    bf16* __restrict__ RW, int M, int N, int K) {
    __shared__ __align__(16) bf16 sXV[8192];
    __shared__ __align__(16) bf16 sXR[8192];
    __shared__ __align__(16) bf16 sWV[8192];
    __shared__ __align__(16) bf16 sWR[8192];

    const int tid  = threadIdx.x;
    const int wave = tid >> 6;
    const int lane = tid & 63;
    const int quad = lane >> 4;
    const int l16  = lane & 15;
    const int m0   = blockIdx.y * 128;
    const int n0   = blockIdx.x * 128;
    const int wm   = (wave >> 1) * 64;
    const int wn   = (wave & 1) * 64;
    const int KS   = K >> 5;  // 32-k slabs per row

    floatx4 accv[4][4], accr[4][4];
#pragma unroll
    for (int i = 0; i < 4; ++i)
#pragma unroll
        for (int j = 0; j < 4; ++j) {
            accv[i][j] = (floatx4){0.f, 0.f, 0.f, 0.f};
            accr[i][j] = (floatx4){0.f, 0.f, 0.f, 0.f};
        }

    // wave w stages row-blocks w and w+4 (2 k-slabs each) of every tensor
    const size_t aoff = ((size_t)((m0 >> 4) + wave) * KS) * 512 + lane * 8;
    const size_t boff = ((size_t)((n0 >> 4) + wave) * KS) * 512 + lane * 8;
    const size_t step4 = (size_t)4 * KS * 512;
    const bf16* gXV0 = XV + aoff;
    const bf16* gXR0 = XR + aoff;
    const bf16* gWV0 = WV + boff;
    const bf16* gWR0 = WR + boff;

    // LDS slot (rb, ks): offset = (rb*2 + ks)*512
    const int d0 = (wave * 2) * 512;
    const int d1 = ((wave + 4) * 2) * 512;
    const int rba = (wave >> 1) * 4;
    const int rbb = (wave & 1) * 4;

    const int iters = K >> 6;
    for (int it = 0; it < iters; ++it) {
        __syncthreads();
        async_cp16(gXV0,                &sXV[d0]);
        async_cp16(gXV0 + 512,          &sXV[d0 + 512]);
        async_cp16(gXV0 + step4,        &sXV[d1]);
        async_cp16(gXV0 + step4 + 512,  &sXV[d1 + 512]);
        async_cp16(gXR0,                &sXR[d0]);
        async_cp16(gXR0 + 512,          &sXR[d0 + 512]);
        async_cp16(gXR0 + step4,        &sXR[d1]);
        async_cp16(gXR0 + step4 + 512,  &sXR[d1 + 512]);
        async_cp16(gWV0,                &sWV[d0]);
        async_cp16(gWV0 + 512,          &sWV[d0 + 512]);
        async_cp16(gWV0 + step4,        &sWV[d1]);
        async_cp16(gWV0 + step4 + 512,  &sWV[d1 + 512]);
        async_cp16(gWR0,                &sWR[d0]);
        async_cp16(gWR0 + 512,          &sWR[d0 + 512]);
        async_cp16(gWR0 + step4,        &sWR[d1]);
        async_cp16(gWR0 + step4 + 512,  &sWR[d1 + 512]);
        gXV0 += 1024; gXR0 += 1024; gWV0 += 1024; gWR0 += 1024;
        __syncthreads();

#pragma unroll
        for (int s = 0; s < 2; ++s) {
            bf16x8 av[4], bv[4];
#pragma unroll
            for (int i = 0; i < 4; ++i)
                av[i] = *(const bf16x8*)&sXV[((rba + i) * 2 + s) * 512 + (lane << 3)];
#pragma unroll
            for (int j = 0; j < 4; ++j)
                bv[j] = *(const bf16x8*)&sWV[((rbb + j) * 2 + s) * 512 + (lane << 3)];
#pragma unroll
            for (int i = 0; i < 4; ++i)
#pragma unroll
                for (int j = 0; j < 4; ++j)
                    accv[i][j] = __builtin_amdgcn_mfma_f32_16x16x32_bf16(
                        av[i], bv[j], accv[i][j], 0, 0, 0);
            bf16x8 ar[4], br[4];
#pragma unroll
            for (int i = 0; i < 4; ++i)
                ar[i] = *(const bf16x8*)&sXR[((rba + i) * 2 + s) * 512 + (lane << 3)];
#pragma unroll
            for (int j = 0; j < 4; ++j)
                br[j] = *(const bf16x8*)&sWR[((rbb + j) * 2 + s) * 512 + (lane << 3)];
#pragma unroll
            for (int i = 0; i < 4; ++i)
#pragma unroll
                for (int j = 0; j < 4; ++j)
                    accr[i][j] = __builtin_amdgcn_mfma_f32_16x16x32_bf16(
                        ar[i], br[j], accr[i][j], 0, 0, 0);
        }
    }

    // epilogue: rwkv = bf16(sigmoid(accr) * accv), swizzled store
    const int rbase = quad * 4;
#pragma unroll
    for (int i = 0; i < 4; ++i) {
        const int rbg = ((m0 + wm) >> 4) + i;
#pragma unroll
        for (int j = 0; j < 4; ++j) {
            const int col = n0 + wn + j * 16 + l16;
            const size_t base = ((size_t)rbg * (N >> 5) + (col >> 5)) * 512 +
                                (size_t)(((col >> 3) & 3) << 4) * 8 + (col & 7);
#pragma unroll
            for (int r = 0; r < 4; ++r) {
                const float sg = 1.0f / (1.0f + __expf(-accr[i][j][r]));
                RW[base + (size_t)(rbase + r) * 8] = (bf16)(sg * accv[i][j][r]);
            }
        }
    }
}

// ---------------------------------------------------------------------------
// out-GEMM, BK=64: Of = A @ Bw^T  (fp32 row-major store). 32KB LDS.
// ---------------------------------------------------------------------------
__global__ __launch_bounds__(256) void gemm_o(
    const bf16* __restrict__ A, const bf16* __restrict__ Bw,
    float* __restrict__ Of, int M, int N, int K) {
    __shared__ __align__(16) bf16 sA[8192];
    __shared__ __align__(16) bf16 sB[8192];

    const int tid  = threadIdx.x;
    const int wave = tid >> 6;
    const int lane = tid & 63;
    const int quad = lane >> 4;
    const int l16  = lane & 15;
    const int m0   = blockIdx.y * 128;
    const int n0   = blockIdx.x * 128;
    const int wm   = (wave >> 1) * 64;
    const int wn   = (wave & 1) * 64;
    const int KS   = K >> 5;

    floatx4 acc[4][4];
#pragma unroll
    for (int i = 0; i < 4; ++i)
#pragma unroll
        for (int j = 0; j < 4; ++j) acc[i][j] = (floatx4){0.f, 0.f, 0.f, 0.f};

    const size_t step4 = (size_t)4 * KS * 512;
    const bf16* gA0 = A + ((size_t)((m0 >> 4) + wave) * KS) * 512 + lane * 8;
    const bf16* gB0 = Bw + ((size_t)((n0 >> 4) + wave) * KS) * 512 + lane * 8;
    const int d0 = (wave * 2) * 512;
    const int d1 = ((wave + 4) * 2) * 512;
    const int rba = (wave >> 1) * 4;
    const int rbb = (wave & 1) * 4;

    const int iters = K >> 6;
    for (int it = 0; it < iters; ++it) {
        __syncthreads();
        async_cp16(gA0,               &sA[d0]);
        async_cp16(gA0 + 512,         &sA[d0 + 512]);
        async_cp16(gA0 + step4,       &sA[d1]);
        async_cp16(gA0 + step4 + 512, &sA[d1 + 512]);
        async_cp16(gB0,               &sB[d0]);
        async_cp16(gB0 + 512,         &sB[d0 + 512]);
        async_cp16(gB0 + step4,       &sB[d1]);
        async_cp16(gB0 + step4 + 512, &sB[d1 + 512]);
        gA0 += 1024; gB0 += 1024;
        __syncthreads();

#pragma unroll
        for (int s = 0; s < 2; ++s) {
            bf16x8 af[4], bf[4];
#pragma unroll
            for (int i = 0; i < 4; ++i)
                af[i] = *(const bf16x8*)&sA[((rba + i) * 2 + s) * 512 + (lane << 3)];
#pragma unroll
            for (int j = 0; j < 4; ++j)
                bf[j] = *(const bf16x8*)&sB[((rbb + j) * 2 + s) * 512 + (lane << 3)];
#pragma unroll
            for (int i = 0; i < 4; ++i)
#pragma unroll
                for (int j = 0; j < 4; ++j)
                    acc[i][j] = __builtin_amdgcn_mfma_f32_16x16x32_bf16(
                        af[i], bf[j], acc[i][j], 0, 0, 0);
        }
    }

    const int rbase = quad * 4;
#pragma unroll
    for (int i = 0; i < 4; ++i) {
#pragma unroll
        for (int j = 0; j < 4; ++j) {
            const int col = n0 + wn + j * 16 + l16;
#pragma unroll
            for (int r = 0; r < 4; ++r) {
                const int row = m0 + wm + i * 16 + rbase + r;
                Of[(size_t)row * N + col] = acc[i][j][r];
            }
        }
    }
}

// ---------------------------------------------------------------------------
// fallback path (small ws): R3's BK=32 3-GEMM pipeline with vbuf in d_out
// ---------------------------------------------------------------------------
template <int EPI>
__global__ __launch_bounds__(256) void gemm_swz(
    const bf16* __restrict__ A, const bf16* __restrict__ Bw,
    const bf16* __restrict__ Vaux, bf16* __restrict__ Ob,
    float* __restrict__ Of, int M, int N, int K) {
    __shared__ __align__(16) bf16 sA[128 * 32];
    __shared__ __align__(16) bf16 sB[128 * 32];

    const int tid  = threadIdx.x;
    const int wave = tid >> 6;
    const int lane = tid & 63;
    const int quad = lane >> 4;
    const int l16  = lane & 15;
    const int m0   = blockIdx.y * 128;
    const int n0   = blockIdx.x * 128;
    const int wm   = (wave >> 1) * 64;
    const int wn   = (wave & 1) * 64;
    const int kslabs = K >> 5;

    floatx4 acc[4][4];
#pragma unroll
    for (int i = 0; i < 4; ++i)
#pragma unroll
        for (int j = 0; j < 4; ++j) acc[i][j] = (floatx4){0.f, 0.f, 0.f, 0.f};

    const bf16* gA0 = A + ((size_t)((m0 >> 4) + wave) * kslabs) * 512 + lane * 8;
    const bf16* gA1 = gA0 + (size_t)4 * kslabs * 512;
    const bf16* gB0 = Bw + ((size_t)((n0 >> 4) + wave) * kslabs) * 512 + lane * 8;
    const bf16* gB1 = gB0 + (size_t)4 * kslabs * 512;
    bf16* lA0 = &sA[wave * 512];
    bf16* lA1 = &sA[2048 + wave * 512];
    bf16* lB0 = &sB[wave * 512];
    bf16* lB1 = &sB[2048 + wave * 512];

    for (int it = 0; it < kslabs; ++it) {
        __syncthreads();
        async_cp16(gA0, lA0);
        async_cp16(gA1, lA1);
        async_cp16(gB0, lB0);
        async_cp16(gB1, lB1);
        gA0 += 512; gA1 += 512; gB0 += 512; gB1 += 512;
        __syncthreads();

        bf16x8 af[4], bfg[4];
#pragma unroll
        for (int i = 0; i < 4; ++i)
            af[i] = *(const bf16x8*)&sA[(((wm >> 4) + i) << 9) + (lane << 3)];
#pragma unroll
        for (int j = 0; j < 4; ++j)
            bfg[j] = *(const bf16x8*)&sB[(((wn >> 4) + j) << 9) + (lane << 3)];
#pragma unroll
        for (int i = 0; i < 4; ++i)
#pragma unroll
            for (int j = 0; j < 4; ++j)
                acc[i][j] = __builtin_amdgcn_mfma_f32_16x16x32_bf16(
                    af[i], bfg[j], acc[i][j], 0, 0, 0);
    }

    const int rbase = quad * 4;
#pragma unroll
    for (int i = 0; i < 4; ++i) {
        const int rb = ((m0 + wm) >> 4) + i;
#pragma unroll
        for (int j = 0; j < 4; ++j) {
            const int col = n0 + wn + j * 16 + l16;
            if (EPI == 2) {
#pragma unroll
                for (int r = 0; r < 4; ++r) {
                    const int row = m0 + wm + i * 16 + rbase + r;
                    Of[(size_t)row * N + col] = acc[i][j][r];
                }
            } else {
                const size_t base = ((size_t)rb * (N >> 5) + (col >> 5)) * 512 +
                                    (size_t)(((col >> 3) & 3) << 4) * 8 + (col & 7);
#pragma unroll
                for (int r = 0; r < 4; ++r) {
                    const size_t o = base + (size_t)(rbase + r) * 8;
                    const float va = acc[i][j][r];
                    if (EPI == 0) {
                        Ob[o] = (bf16)va;
                    } else {
                        const float vv = (float)Vaux[o];
                        const float sg = 1.0f / (1.0f + __expf(-va));
                        Ob[o] = (bf16)(sg * vv);
                    }
                }
            }
        }
    }
}

extern "C" void kernel_launch(void* const* d_in, const int* in_sizes, int n_in,
                              void* d_out, int out_size, void* d_ws, size_t ws_size,
                              hipStream_t stream) {
    // inputs: 0:x 1:time_first 2:tmk 3:tmv 4:tmr 5:xx 6:aa 7:bb 8:pp
    //         9:w_key 10:w_value 11:w_rec 12:w_out
    const int C = in_sizes[1];              // 2048
    const int M = in_sizes[0] / C;          // B*T = 8192
    const size_t MC = (size_t)M * C;
    const size_t CC = (size_t)C * C;

    const float* x   = (const float*)d_in[0];
    const float* tmv = (const float*)d_in[3];
    const float* tmr = (const float*)d_in[4];
    const float* xxp = (const float*)d_in[5];
    const float* wv  = (const float*)d_in[10];
    const float* wr  = (const float*)d_in[11];
    const float* wo  = (const float*)d_in[12];
    float* out = (float*)d_out;

    uint8_t* ws = (uint8_t*)d_ws;
    const size_t need_full = MC * 6 + CC * 6;
    dim3 gridG(C / 128, M / 128);  // (16, 64)

    if (ws_size >= need_full) {
        bf16* xv   = (bf16*)(ws);
        bf16* xr   = (bf16*)(ws + MC * 2);
        bf16* rwkv = (bf16*)(ws + MC * 4);
        bf16* wvb  = (bf16*)(ws + MC * 6);
        bf16* wrb  = (bf16*)(ws + MC * 6 + CC * 2);
        bf16* wob  = (bf16*)(ws + MC * 6 + CC * 4);

        prep_swz<<<dim3(C / 128, M / 16), 256, 0, stream>>>(x, tmv, tmr, xxp, xv, xr, C);
        cvt_swz<<<dim3(C / 128, C / 16, 3), 256, 0, stream>>>(wv, wr, wo, wvb, wrb, wob, C);
        // rwkv = sigmoid(xr@Wr^T) * (xv@Wv^T)   (wkv == v, see analysis)
        gemm_vr<<<gridG, 256, 0, stream>>>(xv, xr, wvb, wrb, rwkv, M, C, C);
        // out = rwkv @ Wo^T
        gemm_o<<<gridG, 256, 0, stream>>>(rwkv, wob, out, M, C, C);
    } else {
        // fallback: park v (bf16) in d_out (fp32 => 2x bytes); consumed by
        // GEMM_r before GEMM_out overwrites d_out.
        bf16* xv   = (bf16*)(ws);
        bf16* xr   = (bf16*)(ws + MC * 2);
        bf16* vbuf = (bf16*)d_out;
        bf16* wvb  = (bf16*)(ws + MC * 4);
        bf16* wrb  = (bf16*)(ws + MC * 4 + CC * 2);
        bf16* wob  = (bf16*)(ws + MC * 4 + CC * 4);
        bf16* rwkv = xv;  // xv dead after GEMM_v

        prep_swz<<<dim3(C / 128, M / 16), 256, 0, stream>>>(x, tmv, tmr, xxp, xv, xr, C);
        cvt_swz<<<dim3(C / 128, C / 16, 3), 256, 0, stream>>>(wv, wr, wo, wvb, wrb, wob, C);
        gemm_swz<0><<<gridG, 256, 0, stream>>>(xv, wvb, nullptr, vbuf, nullptr, M, C, C);
        gemm_swz<1><<<gridG, 256, 0, stream>>>(xr, wrb, vbuf, rwkv, nullptr, M, C, C);
        gemm_swz<2><<<gridG, 256, 0, stream>>>(rwkv, wob, nullptr, nullptr, out, M, C, C);
    }
}

// Round 5
// 372.035 us; speedup vs baseline: 1.6744x; 1.0800x over previous
//
#include <hip/hip_runtime.h>
#include <hip/hip_bf16.h>
#include <cstdint>
#include <cstddef>

using bf16    = __bf16;
using bf16x8  = __attribute__((ext_vector_type(8))) __bf16;
using floatx4 = __attribute__((ext_vector_type(4))) float;

// Swizzled ("packet") layout for all bf16 GEMM operands:
//   packet = 1024B = one (16-row x 32-k) block of a row-major [R x K] matrix
//   packet index  = (row>>4) * (K>>5) + (k>>5)
//   lane l (16B) holds row = 16*(row>>4) + (l&15), k-chunk l>>4 (8 elems)
// => element (row,k) at  packet*512 + (((k>>3)&3)*16 + (row&15))*8 + (k&7)
// Staging reads 1024B contiguous per wave; LDS fragment reads are lane-linear.

__device__ __forceinline__ void async_cp16(const bf16* g, bf16* l) {
    __builtin_amdgcn_global_load_lds(
        (__attribute__((address_space(1))) void*)const_cast<bf16*>(g),
        (__attribute__((address_space(3))) void*)l,
        16, 0, 0);
}

// ---------------------------------------------------------------------------
// prep+cvt fused: yb < prepRows -> token-mix rows of xv/xr;
//                 else          -> fp32->bf16 convert of one weight row-block.
// All outputs swizzled.
// ---------------------------------------------------------------------------
__global__ __launch_bounds__(256) void prep_cvt(
    const float* __restrict__ x, const float* __restrict__ tmv,
    const float* __restrict__ tmr, const float* __restrict__ xxp,
    const float* __restrict__ w0, const float* __restrict__ w1,
    const float* __restrict__ w2, bf16* __restrict__ xv, bf16* __restrict__ xr,
    bf16* __restrict__ o0, bf16* __restrict__ o1, bf16* __restrict__ o2,
    int C, int prepRows) {
    const int t = threadIdx.x;
    const int p = t >> 6, l = t & 63;
    const int c0 = blockIdx.x << 7;
    const int k = c0 + (p << 5) + ((l >> 4) << 3);
    const int yb = blockIdx.y;
    const int C4 = C >> 4;

    if (yb < prepRows) {
        const int r0 = yb << 4;
        const int row = r0 + (l & 15);
        const float4* xi = (const float4*)&x[(size_t)row * C + k];
        float4 a0 = xi[0], a1 = xi[1];
        float4 mv0 = *(const float4*)&tmv[k], mv1 = *(const float4*)&tmv[k + 4];
        float4 mr0 = *(const float4*)&tmr[k], mr1 = *(const float4*)&tmr[k + 4];
        float4 x00 = *(const float4*)&xxp[k], x01 = *(const float4*)&xxp[k + 4];
        float xa[8]  = {a0.x, a0.y, a0.z, a0.w, a1.x, a1.y, a1.z, a1.w};
        float mva[8] = {mv0.x, mv0.y, mv0.z, mv0.w, mv1.x, mv1.y, mv1.z, mv1.w};
        float mra[8] = {mr0.x, mr0.y, mr0.z, mr0.w, mr1.x, mr1.y, mr1.z, mr1.w};
        float x0a[8] = {x00.x, x00.y, x00.z, x00.w, x01.x, x01.y, x01.z, x01.w};
        bf16x8 ov, og;
#pragma unroll
        for (int u = 0; u < 8; ++u) {
            ov[u] = (bf16)(xa[u] * mva[u] + (1.0f - mva[u]) * x0a[u]);
            og[u] = (bf16)(xa[u] * mra[u] + (1.0f - mra[u]) * x0a[u]);
        }
        const size_t off = ((size_t)(r0 >> 4) * (C >> 5) + (c0 >> 5) + p) * 512 + l * 8;
        *(bf16x8*)&xv[off] = ov;
        *(bf16x8*)&xr[off] = og;
    } else {
        int z = yb - prepRows;
        const float* wsrc;
        bf16* wdst;
        if (z < C4) {
            wsrc = w0; wdst = o0;
        } else if (z < 2 * C4) {
            wsrc = w1; wdst = o1; z -= C4;
        } else {
            wsrc = w2; wdst = o2; z -= 2 * C4;
        }
        const int r0 = z << 4;
        const int row = r0 + (l & 15);
        const float4* wi = (const float4*)&wsrc[(size_t)row * C + k];
        float4 a0 = wi[0], a1 = wi[1];
        float wa[8] = {a0.x, a0.y, a0.z, a0.w, a1.x, a1.y, a1.z, a1.w};
        bf16x8 ov;
#pragma unroll
        for (int u = 0; u < 8; ++u) ov[u] = (bf16)wa[u];
        const size_t off = ((size_t)(r0 >> 4) * (C >> 5) + (c0 >> 5) + p) * 512 + l * 8;
        *(bf16x8*)&wdst[off] = ov;
    }
}

// ---------------------------------------------------------------------------
// FUSED v/r GEMM, BK=64, 128x128 tile, XCD-swizzled 1D grid:
//   c = bid&7 (XCD), mt = c*8 + (t&7), nt = t>>3  -> each XCD owns an
//   8-m-tile band so xv/xr staging hits its own L2 (shorter barrier drains).
// ---------------------------------------------------------------------------
__global__ __launch_bounds__(256, 2) void gemm_vr(
    const bf16* __restrict__ XV, const bf16* __restrict__ XR,
    const bf16* __restrict__ WV, const bf16* __restrict__ WR,
    bf16* __restrict__ RW, int M, int N, int K) {
    __shared__ __align__(16) bf16 sXV[8192];
    __shared__ __align__(16) bf16 sXR[8192];
    __shared__ __align__(16) bf16 sWV[8192];
    __shared__ __align__(16) bf16 sWR[8192];

    const int bid = blockIdx.x;
    const int xcd = bid & 7;
    const int tt  = bid >> 3;
    const int mt  = xcd * 8 + (tt & 7);   // M/128 = 64 tiles
    const int nt  = tt >> 3;              // N/128 = 16 tiles

    const int tid  = threadIdx.x;
    const int wave = tid >> 6;
    const int lane = tid & 63;
    const int quad = lane >> 4;
    const int l16  = lane & 15;
    const int m0   = mt * 128;
    const int n0   = nt * 128;
    const int wm   = (wave >> 1) * 64;
    const int wn   = (wave & 1) * 64;
    const int KS   = K >> 5;

    floatx4 accv[4][4], accr[4][4];
#pragma unroll
    for (int i = 0; i < 4; ++i)
#pragma unroll
        for (int j = 0; j < 4; ++j) {
            accv[i][j] = (floatx4){0.f, 0.f, 0.f, 0.f};
            accr[i][j] = (floatx4){0.f, 0.f, 0.f, 0.f};
        }

    const size_t aoff = ((size_t)((m0 >> 4) + wave) * KS) * 512 + lane * 8;
    const size_t boff = ((size_t)((n0 >> 4) + wave) * KS) * 512 + lane * 8;
    const size_t step4 = (size_t)4 * KS * 512;
    const bf16* gXV0 = XV + aoff;
    const bf16* gXR0 = XR + aoff;
    const bf16* gWV0 = WV + boff;
    const bf16* gWR0 = WR + boff;

    const int d0 = (wave * 2) * 512;
    const int d1 = ((wave + 4) * 2) * 512;
    const int rba = (wave >> 1) * 4;
    const int rbb = (wave & 1) * 4;

    const int iters = K >> 6;
    for (int it = 0; it < iters; ++it) {
        __syncthreads();
        async_cp16(gXV0,                &sXV[d0]);
        async_cp16(gXV0 + 512,          &sXV[d0 + 512]);
        async_cp16(gXV0 + step4,        &sXV[d1]);
        async_cp16(gXV0 + step4 + 512,  &sXV[d1 + 512]);
        async_cp16(gXR0,                &sXR[d0]);
        async_cp16(gXR0 + 512,          &sXR[d0 + 512]);
        async_cp16(gXR0 + step4,        &sXR[d1]);
        async_cp16(gXR0 + step4 + 512,  &sXR[d1 + 512]);
        async_cp16(gWV0,                &sWV[d0]);
        async_cp16(gWV0 + 512,          &sWV[d0 + 512]);
        async_cp16(gWV0 + step4,        &sWV[d1]);
        async_cp16(gWV0 + step4 + 512,  &sWV[d1 + 512]);
        async_cp16(gWR0,                &sWR[d0]);
        async_cp16(gWR0 + 512,          &sWR[d0 + 512]);
        async_cp16(gWR0 + step4,        &sWR[d1]);
        async_cp16(gWR0 + step4 + 512,  &sWR[d1 + 512]);
        gXV0 += 1024; gXR0 += 1024; gWV0 += 1024; gWR0 += 1024;
        __syncthreads();

#pragma unroll
        for (int s = 0; s < 2; ++s) {
            bf16x8 av[4], bv[4];
#pragma unroll
            for (int i = 0; i < 4; ++i)
                av[i] = *(const bf16x8*)&sXV[((rba + i) * 2 + s) * 512 + (lane << 3)];
#pragma unroll
            for (int j = 0; j < 4; ++j)
                bv[j] = *(const bf16x8*)&sWV[((rbb + j) * 2 + s) * 512 + (lane << 3)];
#pragma unroll
            for (int i = 0; i < 4; ++i)
#pragma unroll
                for (int j = 0; j < 4; ++j)
                    accv[i][j] = __builtin_amdgcn_mfma_f32_16x16x32_bf16(
                        av[i], bv[j], accv[i][j], 0, 0, 0);
            bf16x8 ar[4], br[4];
#pragma unroll
            for (int i = 0; i < 4; ++i)
                ar[i] = *(const bf16x8*)&sXR[((rba + i) * 2 + s) * 512 + (lane << 3)];
#pragma unroll
            for (int j = 0; j < 4; ++j)
                br[j] = *(const bf16x8*)&sWR[((rbb + j) * 2 + s) * 512 + (lane << 3)];
#pragma unroll
            for (int i = 0; i < 4; ++i)
#pragma unroll
                for (int j = 0; j < 4; ++j)
                    accr[i][j] = __builtin_amdgcn_mfma_f32_16x16x32_bf16(
                        ar[i], br[j], accr[i][j], 0, 0, 0);
        }
    }

    // epilogue: rwkv = bf16(sigmoid(accr) * accv), swizzled store
    const int rbase = quad * 4;
#pragma unroll
    for (int i = 0; i < 4; ++i) {
        const int rbg = ((m0 + wm) >> 4) + i;
#pragma unroll
        for (int j = 0; j < 4; ++j) {
            const int col = n0 + wn + j * 16 + l16;
            const size_t base = ((size_t)rbg * (N >> 5) + (col >> 5)) * 512 +
                                (size_t)(((col >> 3) & 3) << 4) * 8 + (col & 7);
#pragma unroll
            for (int r = 0; r < 4; ++r) {
                const float sg = 1.0f / (1.0f + __expf(-accr[i][j][r]));
                RW[base + (size_t)(rbase + r) * 8] = (bf16)(sg * accv[i][j][r]);
            }
        }
    }
}

// ---------------------------------------------------------------------------
// out-GEMM, BK=64, 128x256 tile (64 MFMA per drain), XCD-swizzled 1D grid.
// Of = A @ Bw^T, fp32 row-major. LDS: sA 16KB + sB 32KB = 48KB.
// ---------------------------------------------------------------------------
__global__ __launch_bounds__(256, 2) void gemm_o(
    const bf16* __restrict__ A, const bf16* __restrict__ Bw,
    float* __restrict__ Of, int M, int N, int K) {
    __shared__ __align__(16) bf16 sA[8192];
    __shared__ __align__(16) bf16 sB[16384];

    const int bid = blockIdx.x;
    const int xcd = bid & 7;
    const int tt  = bid >> 3;
    const int mt  = xcd * 8 + (tt & 7);   // M/128 = 64 tiles
    const int nt  = tt >> 3;              // N/256 = 8 tiles

    const int tid  = threadIdx.x;
    const int wave = tid >> 6;
    const int lane = tid & 63;
    const int quad = lane >> 4;
    const int l16  = lane & 15;
    const int m0   = mt * 128;
    const int n0   = nt * 256;
    const int wm   = (wave >> 1) * 64;
    const int wnb  = (wave & 1) * 128;
    const int KS   = K >> 5;

    floatx4 acc[4][8];
#pragma unroll
    for (int i = 0; i < 4; ++i)
#pragma unroll
        for (int j = 0; j < 8; ++j) acc[i][j] = (floatx4){0.f, 0.f, 0.f, 0.f};

    const size_t step4 = (size_t)4 * KS * 512;
    const bf16* gA0 = A + ((size_t)((m0 >> 4) + wave) * KS) * 512 + lane * 8;
    const bf16* gB0 = Bw + ((size_t)((n0 >> 4) + wave) * KS) * 512 + lane * 8;
    const int dA0 = (wave * 2) * 512;
    const int dA1 = ((wave + 4) * 2) * 512;
    const int rba = (wave >> 1) * 4;
    const int rbb = (wave & 1) * 8;

    const int iters = K >> 6;
    for (int it = 0; it < iters; ++it) {
        __syncthreads();
        async_cp16(gA0,               &sA[dA0]);
        async_cp16(gA0 + 512,         &sA[dA0 + 512]);
        async_cp16(gA0 + step4,       &sA[dA1]);
        async_cp16(gA0 + step4 + 512, &sA[dA1 + 512]);
#pragma unroll
        for (int u = 0; u < 4; ++u) {
            const int dB = ((wave + 4 * u) * 2) * 512;
            async_cp16(gB0 + u * step4,       &sB[dB]);
            async_cp16(gB0 + u * step4 + 512, &sB[dB + 512]);
        }
        gA0 += 1024; gB0 += 1024;
        __syncthreads();

#pragma unroll
        for (int s = 0; s < 2; ++s) {
            bf16x8 af[4], bfg[8];
#pragma unroll
            for (int i = 0; i < 4; ++i)
                af[i] = *(const bf16x8*)&sA[((rba + i) * 2 + s) * 512 + (lane << 3)];
#pragma unroll
            for (int j = 0; j < 8; ++j)
                bfg[j] = *(const bf16x8*)&sB[((rbb + j) * 2 + s) * 512 + (lane << 3)];
#pragma unroll
            for (int i = 0; i < 4; ++i)
#pragma unroll
                for (int j = 0; j < 8; ++j)
                    acc[i][j] = __builtin_amdgcn_mfma_f32_16x16x32_bf16(
                        af[i], bfg[j], acc[i][j], 0, 0, 0);
        }
    }

    const int rbase = quad * 4;
#pragma unroll
    for (int i = 0; i < 4; ++i) {
#pragma unroll
        for (int j = 0; j < 8; ++j) {
            const int col = n0 + wnb + j * 16 + l16;
#pragma unroll
            for (int r = 0; r < 4; ++r) {
                const int row = m0 + wm + i * 16 + rbase + r;
                Of[(size_t)row * N + col] = acc[i][j][r];
            }
        }
    }
}

// ---------------------------------------------------------------------------
// fallback path (small ws): BK=32 3-GEMM pipeline with vbuf in d_out
// ---------------------------------------------------------------------------
template <int EPI>
__global__ __launch_bounds__(256) void gemm_swz(
    const bf16* __restrict__ A, const bf16* __restrict__ Bw,
    const bf16* __restrict__ Vaux, bf16* __restrict__ Ob,
    float* __restrict__ Of, int M, int N, int K) {
    __shared__ __align__(16) bf16 sA[128 * 32];
    __shared__ __align__(16) bf16 sB[128 * 32];

    const int tid  = threadIdx.x;
    const int wave = tid >> 6;
    const int lane = tid & 63;
    const int quad = lane >> 4;
    const int l16  = lane & 15;
    const int m0   = blockIdx.y * 128;
    const int n0   = blockIdx.x * 128;
    const int wm   = (wave >> 1) * 64;
    const int wn   = (wave & 1) * 64;
    const int kslabs = K >> 5;

    floatx4 acc[4][4];
#pragma unroll
    for (int i = 0; i < 4; ++i)
#pragma unroll
        for (int j = 0; j < 4; ++j) acc[i][j] = (floatx4){0.f, 0.f, 0.f, 0.f};

    const bf16* gA0 = A + ((size_t)((m0 >> 4) + wave) * kslabs) * 512 + lane * 8;
    const bf16* gA1 = gA0 + (size_t)4 * kslabs * 512;
    const bf16* gB0 = Bw + ((size_t)((n0 >> 4) + wave) * kslabs) * 512 + lane * 8;
    const bf16* gB1 = gB0 + (size_t)4 * kslabs * 512;
    bf16* lA0 = &sA[wave * 512];
    bf16* lA1 = &sA[2048 + wave * 512];
    bf16* lB0 = &sB[wave * 512];
    bf16* lB1 = &sB[2048 + wave * 512];

    for (int it = 0; it < kslabs; ++it) {
        __syncthreads();
        async_cp16(gA0, lA0);
        async_cp16(gA1, lA1);
        async_cp16(gB0, lB0);
        async_cp16(gB1, lB1);
        gA0 += 512; gA1 += 512; gB0 += 512; gB1 += 512;
        __syncthreads();

        bf16x8 af[4], bfg[4];
#pragma unroll
        for (int i = 0; i < 4; ++i)
            af[i] = *(const bf16x8*)&sA[(((wm >> 4) + i) << 9) + (lane << 3)];
#pragma unroll
        for (int j = 0; j < 4; ++j)
            bfg[j] = *(const bf16x8*)&sB[(((wn >> 4) + j) << 9) + (lane << 3)];
#pragma unroll
        for (int i = 0; i < 4; ++i)
#pragma unroll
            for (int j = 0; j < 4; ++j)
                acc[i][j] = __builtin_amdgcn_mfma_f32_16x16x32_bf16(
                    af[i], bfg[j], acc[i][j], 0, 0, 0);
    }

    const int rbase = quad * 4;
#pragma unroll
    for (int i = 0; i < 4; ++i) {
        const int rb = ((m0 + wm) >> 4) + i;
#pragma unroll
        for (int j = 0; j < 4; ++j) {
            const int col = n0 + wn + j * 16 + l16;
            if (EPI == 2) {
#pragma unroll
                for (int r = 0; r < 4; ++r) {
                    const int row = m0 + wm + i * 16 + rbase + r;
                    Of[(size_t)row * N + col] = acc[i][j][r];
                }
            } else {
                const size_t base = ((size_t)rb * (N >> 5) + (col >> 5)) * 512 +
                                    (size_t)(((col >> 3) & 3) << 4) * 8 + (col & 7);
#pragma unroll
                for (int r = 0; r < 4; ++r) {
                    const size_t o = base + (size_t)(rbase + r) * 8;
                    const float va = acc[i][j][r];
                    if (EPI == 0) {
                        Ob[o] = (bf16)va;
                    } else {
                        const float vv = (float)Vaux[o];
                        const float sg = 1.0f / (1.0f + __expf(-va));
                        Ob[o] = (bf16)(sg * vv);
                    }
                }
            }
        }
    }
}

extern "C" void kernel_launch(void* const* d_in, const int* in_sizes, int n_in,
                              void* d_out, int out_size, void* d_ws, size_t ws_size,
                              hipStream_t stream) {
    // inputs: 0:x 1:time_first 2:tmk 3:tmv 4:tmr 5:xx 6:aa 7:bb 8:pp
    //         9:w_key 10:w_value 11:w_rec 12:w_out
    const int C = in_sizes[1];              // 2048
    const int M = in_sizes[0] / C;          // B*T = 8192
    const size_t MC = (size_t)M * C;
    const size_t CC = (size_t)C * C;

    const float* x   = (const float*)d_in[0];
    const float* tmv = (const float*)d_in[3];
    const float* tmr = (const float*)d_in[4];
    const float* xxp = (const float*)d_in[5];
    const float* wv  = (const float*)d_in[10];
    const float* wr  = (const float*)d_in[11];
    const float* wo  = (const float*)d_in[12];
    float* out = (float*)d_out;

    uint8_t* ws = (uint8_t*)d_ws;
    const size_t need_full = MC * 6 + CC * 6;
    const int prepRows = M / 16;
    dim3 gridP(C / 128, M / 16 + 3 * (C / 16));

    if (ws_size >= need_full) {
        bf16* xv   = (bf16*)(ws);
        bf16* xr   = (bf16*)(ws + MC * 2);
        bf16* rwkv = (bf16*)(ws + MC * 4);
        bf16* wvb  = (bf16*)(ws + MC * 6);
        bf16* wrb  = (bf16*)(ws + MC * 6 + CC * 2);
        bf16* wob  = (bf16*)(ws + MC * 6 + CC * 4);

        prep_cvt<<<gridP, 256, 0, stream>>>(x, tmv, tmr, xxp, wv, wr, wo,
                                            xv, xr, wvb, wrb, wob, C, prepRows);
        // rwkv = sigmoid(xr@Wr^T) * (xv@Wv^T)   (wkv == v, see analysis)
        gemm_vr<<<(M / 128) * (C / 128), 256, 0, stream>>>(xv, xr, wvb, wrb, rwkv,
                                                           M, C, C);
        // out = rwkv @ Wo^T   (128x256 tiles)
        gemm_o<<<(M / 128) * (C / 256), 256, 0, stream>>>(rwkv, wob, out, M, C, C);
    } else {
        // fallback: park v (bf16) in d_out (fp32 => 2x bytes); consumed by
        // GEMM_r before GEMM_out overwrites d_out.
        bf16* xv   = (bf16*)(ws);
        bf16* xr   = (bf16*)(ws + MC * 2);
        bf16* vbuf = (bf16*)d_out;
        bf16* wvb  = (bf16*)(ws + MC * 4);
        bf16* wrb  = (bf16*)(ws + MC * 4 + CC * 2);
        bf16* wob  = (bf16*)(ws + MC * 4 + CC * 4);
        bf16* rwkv = xv;  // xv dead after GEMM_v

        dim3 gridG(C / 128, M / 128);
        prep_cvt<<<gridP, 256, 0, stream>>>(x, tmv, tmr, xxp, wv, wr, wo,
                                            xv, xr, wvb, wrb, wob, C, prepRows);
        gemm_swz<0><<<gridG, 256, 0, stream>>>(xv, wvb, nullptr, vbuf, nullptr, M, C, C);
        gemm_swz<1><<<gridG, 256, 0, stream>>>(xr, wrb, vbuf, rwkv, nullptr, M, C, C);
        gemm_swz<2><<<gridG, 256, 0, stream>>>(rwkv, wob, nullptr, nullptr, out, M, C, C);
    }
}